// Round 2
// baseline (523.193 us; speedup 1.0000x reference)
//
#include <hip/hip_runtime.h>
#include <hip/hip_bf16.h>

// SoftDecisionTree pipeline:
//   ps   = sigmoid(xs @ W^T + b)          gemm1_sigmoid_kernel (bf16 MFMA)
//   lf   = tree path products (bf16)      tree_kernel
//   dT   = softmax(leaf_params)^T (bf16)  softmax_transpose_kernel
//   out  = lf @ dT^T                      gemm2_kernel (bf16 MFMA)

typedef __bf16 bf16x8 __attribute__((ext_vector_type(8)));
typedef float f32x4 __attribute__((ext_vector_type(4)));

#define B_DIM 8192
#define F_DIM 4096
#define NI 511
#define NL 512
#define K_DIM 1000
#define KPAD 1024

// round-to-nearest-even fp32 -> bf16 (bit pattern in low 16)
__device__ inline unsigned short f2bf(float f) {
    unsigned int u = __float_as_uint(f);
    return (unsigned short)((u + 0x7FFFu + ((u >> 16) & 1u)) >> 16);
}

__device__ inline unsigned int pk_bf16(float a, float b) {
    return (unsigned int)f2bf(a) | ((unsigned int)f2bf(b) << 16);
}

// ---------------- GEMM1: ps = sigmoid(xs @ W^T + b) ----------------
// A = xs (8192 x 4096 fp32), B = W (511 x 4096 fp32, padded to 512 with 0)
// C = ps (8192 x 512 fp32). Tile 128x128, BK=64, 4 waves, 16x16x32 bf16 MFMA.
__global__ __launch_bounds__(256) void gemm1_sigmoid_kernel(
    const float* __restrict__ xs, const float* __restrict__ W,
    const float* __restrict__ bvec, float* __restrict__ ps)
{
    __shared__ __align__(16) unsigned short Al[128 * 64];
    __shared__ __align__(16) unsigned short Bl[128 * 64];

    const int tid = threadIdx.x;
    const int m0 = blockIdx.y * 128;
    const int n0 = blockIdx.x * 128;

    const int lane = tid & 63;
    const int wave = tid >> 6;
    const int wm = (wave >> 1) * 64;
    const int wn = (wave & 1) * 64;
    const int quad = lane >> 4;
    const int l16 = lane & 15;

    const int srow = tid >> 3;        // 0..31
    const int skc  = (tid & 7) * 8;   // 0..56

    const f32x4 zero = {0.f, 0.f, 0.f, 0.f};
    f32x4 acc[4][4];
#pragma unroll
    for (int i = 0; i < 4; ++i)
#pragma unroll
        for (int j = 0; j < 4; ++j) acc[i][j] = zero;

    for (int k0 = 0; k0 < F_DIM; k0 += 64) {
        // stage A: 128 rows x 64 k, fp32 -> bf16, contiguous LDS writes
#pragma unroll
        for (int w = 0; w < 4; ++w) {
            const int row = w * 32 + srow;
            const float4* g = (const float4*)(xs + (size_t)(m0 + row) * F_DIM + k0 + skc);
            const float4 v0 = g[0];
            const float4 v1 = g[1];
            uint4 h;
            h.x = pk_bf16(v0.x, v0.y);
            h.y = pk_bf16(v0.z, v0.w);
            h.z = pk_bf16(v1.x, v1.y);
            h.w = pk_bf16(v1.z, v1.w);
            *(uint4*)&Al[row * 64 + skc] = h;
        }
        // stage B (W), rows >= 511 are zero-padded
#pragma unroll
        for (int w = 0; w < 4; ++w) {
            const int row = w * 32 + srow;
            const int n = n0 + row;
            float4 v0 = {0.f, 0.f, 0.f, 0.f};
            float4 v1 = {0.f, 0.f, 0.f, 0.f};
            if (n < NI) {
                const float4* g = (const float4*)(W + (size_t)n * F_DIM + k0 + skc);
                v0 = g[0];
                v1 = g[1];
            }
            uint4 h;
            h.x = pk_bf16(v0.x, v0.y);
            h.y = pk_bf16(v0.z, v0.w);
            h.z = pk_bf16(v1.x, v1.y);
            h.w = pk_bf16(v1.z, v1.w);
            *(uint4*)&Bl[row * 64 + skc] = h;
        }
        __syncthreads();
#pragma unroll
        for (int kk = 0; kk < 64; kk += 32) {
            const int kb = kk + quad * 8;
            bf16x8 a[4], b[4];
#pragma unroll
            for (int i = 0; i < 4; ++i)
                a[i] = *(const bf16x8*)&Al[(wm + i * 16 + l16) * 64 + kb];
#pragma unroll
            for (int j = 0; j < 4; ++j)
                b[j] = *(const bf16x8*)&Bl[(wn + j * 16 + l16) * 64 + kb];
#pragma unroll
            for (int i = 0; i < 4; ++i)
#pragma unroll
                for (int j = 0; j < 4; ++j)
                    acc[i][j] = __builtin_amdgcn_mfma_f32_16x16x32_bf16(a[i], b[j], acc[i][j], 0, 0, 0);
        }
        __syncthreads();
    }

    // epilogue: sigmoid(acc + b[n]) -> ps  (D: row = quad*4 + r, col = lane&15)
#pragma unroll
    for (int i = 0; i < 4; ++i) {
        const int mbase = m0 + wm + i * 16 + quad * 4;
#pragma unroll
        for (int j = 0; j < 4; ++j) {
            const int n = n0 + wn + j * 16 + l16;
            const float bv = (n < NI) ? bvec[n] : 0.0f;
#pragma unroll
            for (int r = 0; r < 4; ++r) {
                const float x = acc[i][j][r] + bv;
                ps[(size_t)(mbase + r) * NL + n] = 1.0f / (1.0f + __expf(-x));
            }
        }
    }
}

// ---------------- tree: leaf_prob (bf16) from ps ----------------
__global__ __launch_bounds__(64) void tree_kernel(
    const float* __restrict__ ps, unsigned short* __restrict__ leafbf)
{
    __shared__ __align__(16) float prow[NL];
    const int row = blockIdx.x;
    const int lane = threadIdx.x;

    const float4* src = (const float4*)(ps + (size_t)row * NL);
    ((float4*)prow)[lane] = src[lane];
    ((float4*)prow)[lane + 64] = src[lane + 64];
    __syncthreads();

    // leaf j = lane*8 + jj; bits MSB..LSB: bits 8..3 = lane bits 5..0, bits 2..0 = jj
    float pre = 1.0f;
    int pnode = 0;
#pragma unroll
    for (int t = 5; t >= 0; --t) {
        const int bit = (lane >> t) & 1;
        const float p = prow[pnode];
        pre *= bit ? p : (1.0f - p);
        pnode = 2 * pnode + 1 + bit;
    }
    unsigned short outs[8];
#pragma unroll
    for (int jj = 0; jj < 8; ++jj) {
        float prob = pre;
        int node = pnode;
#pragma unroll
        for (int t = 2; t >= 0; --t) {
            const int bit = (jj >> t) & 1;
            const float p = prow[node];
            prob *= bit ? p : (1.0f - p);
            node = 2 * node + 1 + bit;
        }
        outs[jj] = f2bf(prob);
    }
    uint4 r;
    r.x = (unsigned int)outs[0] | ((unsigned int)outs[1] << 16);
    r.y = (unsigned int)outs[2] | ((unsigned int)outs[3] << 16);
    r.z = (unsigned int)outs[4] | ((unsigned int)outs[5] << 16);
    r.w = (unsigned int)outs[6] | ((unsigned int)outs[7] << 16);
    *(uint4*)(leafbf + (size_t)row * NL + lane * 8) = r;
}

// ---------------- softmax + transpose: dT[n][k] = softmax(leaf_params[k])[n] ----------------
__device__ inline float waveMax(float v) {
#pragma unroll
    for (int off = 32; off; off >>= 1) v = fmaxf(v, __shfl_down(v, off, 64));
    return v;
}
__device__ inline float waveSum(float v) {
#pragma unroll
    for (int off = 32; off; off >>= 1) v += __shfl_down(v, off, 64);
    return v;
}

__global__ __launch_bounds__(256) void softmax_transpose_kernel(
    const float* __restrict__ lp, unsigned short* __restrict__ dT)
{
    __shared__ float sred[8];
    const int k = blockIdx.x;   // leaf index 0..511
    const int tid = threadIdx.x;
    const int lane = tid & 63;
    const int wave = tid >> 6;
    const float* rowp = lp + (size_t)k * K_DIM;

    float vals[4];
    float mx = -3.0e38f;
#pragma unroll
    for (int c = 0; c < 4; ++c) {
        const int n = tid + c * 256;
        vals[c] = (n < K_DIM) ? rowp[n] : -3.0e38f;
        mx = fmaxf(mx, vals[c]);
    }
    mx = waveMax(mx);
    if (lane == 0) sred[wave] = mx;
    __syncthreads();
    const float gmax = fmaxf(fmaxf(sred[0], sred[1]), fmaxf(sred[2], sred[3]));

    float sum = 0.f;
#pragma unroll
    for (int c = 0; c < 4; ++c) {
        const int n = tid + c * 256;
        const float e = (n < K_DIM) ? __expf(vals[c] - gmax) : 0.f;
        vals[c] = e;
        sum += e;
    }
    sum = waveSum(sum);
    if (lane == 0) sred[4 + wave] = sum;
    __syncthreads();
    const float inv = 1.0f / (sred[4] + sred[5] + sred[6] + sred[7]);
#pragma unroll
    for (int c = 0; c < 4; ++c) {
        const int n = tid + c * 256;
        if (n < K_DIM) dT[(size_t)n * NL + k] = f2bf(vals[c] * inv);
    }
}

// ---------------- GEMM2: out = leaf_prob @ dists ----------------
// A = leafbf (8192 x 512 bf16), B = dT (1024 x 512 bf16, rows >=1000 garbage/masked)
// C = out (8192 x 1000 fp32)
__global__ __launch_bounds__(256) void gemm2_kernel(
    const unsigned short* __restrict__ A, const unsigned short* __restrict__ Bm,
    float* __restrict__ out)
{
    __shared__ __align__(16) unsigned short Al[128 * 64];
    __shared__ __align__(16) unsigned short Bl[128 * 64];

    const int tid = threadIdx.x;
    const int m0 = blockIdx.y * 128;
    const int n0 = blockIdx.x * 128;

    const int lane = tid & 63;
    const int wave = tid >> 6;
    const int wm = (wave >> 1) * 64;
    const int wn = (wave & 1) * 64;
    const int quad = lane >> 4;
    const int l16 = lane & 15;

    const f32x4 zero = {0.f, 0.f, 0.f, 0.f};
    f32x4 acc[4][4];
#pragma unroll
    for (int i = 0; i < 4; ++i)
#pragma unroll
        for (int j = 0; j < 4; ++j) acc[i][j] = zero;

    for (int k0 = 0; k0 < NL; k0 += 64) {
#pragma unroll
        for (int w = 0; w < 4; ++w) {
            const int c = w * 256 + tid;
            const int row = c >> 3;
            const int kc = (c & 7) * 8;
            *(uint4*)&Al[row * 64 + kc] =
                *(const uint4*)(A + (size_t)(m0 + row) * NL + k0 + kc);
        }
#pragma unroll
        for (int w = 0; w < 4; ++w) {
            const int c = w * 256 + tid;
            const int row = c >> 3;
            const int kc = (c & 7) * 8;
            *(uint4*)&Bl[row * 64 + kc] =
                *(const uint4*)(Bm + (size_t)(n0 + row) * NL + k0 + kc);
        }
        __syncthreads();
#pragma unroll
        for (int kk = 0; kk < 64; kk += 32) {
            const int kb = kk + quad * 8;
            bf16x8 a[4], b[4];
#pragma unroll
            for (int i = 0; i < 4; ++i)
                a[i] = *(const bf16x8*)&Al[(wm + i * 16 + l16) * 64 + kb];
#pragma unroll
            for (int j = 0; j < 4; ++j)
                b[j] = *(const bf16x8*)&Bl[(wn + j * 16 + l16) * 64 + kb];
#pragma unroll
            for (int i = 0; i < 4; ++i)
#pragma unroll
                for (int j = 0; j < 4; ++j)
                    acc[i][j] = __builtin_amdgcn_mfma_f32_16x16x32_bf16(a[i], b[j], acc[i][j], 0, 0, 0);
        }
        __syncthreads();
    }

#pragma unroll
    for (int i = 0; i < 4; ++i) {
        const int mbase = m0 + wm + i * 16 + quad * 4;
#pragma unroll
        for (int j = 0; j < 4; ++j) {
            const int n = n0 + wn + j * 16 + l16;
            if (n < K_DIM) {
#pragma unroll
                for (int r = 0; r < 4; ++r)
                    out[(size_t)(mbase + r) * K_DIM + n] = acc[i][j][r];
            }
        }
    }
}

extern "C" void kernel_launch(void* const* d_in, const int* in_sizes, int n_in,
                              void* d_out, int out_size, void* d_ws, size_t ws_size,
                              hipStream_t stream) {
    const float* xs = (const float*)d_in[0];
    const float* W  = (const float*)d_in[1];
    const float* b  = (const float*)d_in[2];
    const float* lp = (const float*)d_in[3];
    float* out = (float*)d_out;

    char* ws = (char*)d_ws;
    float* ps = (float*)ws;                                        // 8192*512*4  = 16 MB
    unsigned short* leafbf = (unsigned short*)(ws + 16777216);     // 8192*512*2  = 8 MB
    unsigned short* dT = (unsigned short*)(ws + 16777216 + 8388608); // 1024*512*2 = 1 MB

    hipLaunchKernelGGL(gemm1_sigmoid_kernel, dim3(NL / 128, B_DIM / 128), dim3(256), 0, stream,
                       xs, W, b, ps);
    hipLaunchKernelGGL(softmax_transpose_kernel, dim3(NL), dim3(256), 0, stream, lp, dT);
    hipLaunchKernelGGL(tree_kernel, dim3(B_DIM), dim3(64), 0, stream, ps, leafbf);
    hipLaunchKernelGGL(gemm2_kernel, dim3(KPAD / 128, B_DIM / 128), dim3(256), 0, stream,
                       leafbf, dT, out);
}

// Round 3
// 407.428 us; speedup vs baseline: 1.2841x; 1.2841x over previous
//
#include <hip/hip_runtime.h>
#include <hip/hip_bf16.h>

// SoftDecisionTree pipeline (R2: split-K GEMM1 + fused reduce/sigmoid/tree):
//   logits_s = xs @ W^T (k-slice s)        gemm1_kernel (bf16 MFMA, gridDim.z=S)
//   lf   = tree(sigmoid(sum_s + b))        reduce_tree_kernel (bf16 out)
//   dT   = softmax(leaf_params)^T (bf16)   softmax_transpose_kernel
//   out  = lf @ dT^T                       gemm2_kernel (bf16 MFMA, 128x64 tile)

typedef __bf16 bf16x8 __attribute__((ext_vector_type(8)));
typedef float f32x4 __attribute__((ext_vector_type(4)));

#define B_DIM 8192
#define F_DIM 4096
#define NI 511
#define NL 512
#define K_DIM 1000
#define KPAD 1024

// round-to-nearest-even fp32 -> bf16 (bit pattern in low 16)
__device__ inline unsigned short f2bf(float f) {
    unsigned int u = __float_as_uint(f);
    return (unsigned short)((u + 0x7FFFu + ((u >> 16) & 1u)) >> 16);
}

__device__ inline unsigned int pk_bf16(float a, float b) {
    return (unsigned int)f2bf(a) | ((unsigned int)f2bf(b) << 16);
}

// ---------------- GEMM1 (split-K): part[z] = xs @ W^T over k-slice z ----------------
// Tile 128x128, BK=64, 4 waves, 16x16x32 bf16 MFMA. No bias/sigmoid here.
__global__ __launch_bounds__(256) void gemm1_kernel(
    const float* __restrict__ xs, const float* __restrict__ W,
    float* __restrict__ part, int kchunk)
{
    __shared__ __align__(16) unsigned short Al[128 * 64];
    __shared__ __align__(16) unsigned short Bl[128 * 64];

    const int tid = threadIdx.x;
    const int m0 = blockIdx.y * 128;
    const int n0 = blockIdx.x * 128;
    const int kbeg = blockIdx.z * kchunk;
    const int kend = kbeg + kchunk;

    const int lane = tid & 63;
    const int wave = tid >> 6;
    const int wm = (wave >> 1) * 64;
    const int wn = (wave & 1) * 64;
    const int quad = lane >> 4;
    const int l16 = lane & 15;

    const int srow = tid >> 3;        // 0..31
    const int skc  = (tid & 7) * 8;   // 0..56

    const f32x4 zero = {0.f, 0.f, 0.f, 0.f};
    f32x4 acc[4][4];
#pragma unroll
    for (int i = 0; i < 4; ++i)
#pragma unroll
        for (int j = 0; j < 4; ++j) acc[i][j] = zero;

    for (int k0 = kbeg; k0 < kend; k0 += 64) {
#pragma unroll
        for (int w = 0; w < 4; ++w) {
            const int row = w * 32 + srow;
            const float4* g = (const float4*)(xs + (size_t)(m0 + row) * F_DIM + k0 + skc);
            const float4 v0 = g[0];
            const float4 v1 = g[1];
            uint4 h;
            h.x = pk_bf16(v0.x, v0.y);
            h.y = pk_bf16(v0.z, v0.w);
            h.z = pk_bf16(v1.x, v1.y);
            h.w = pk_bf16(v1.z, v1.w);
            *(uint4*)&Al[row * 64 + skc] = h;
        }
#pragma unroll
        for (int w = 0; w < 4; ++w) {
            const int row = w * 32 + srow;
            const int n = n0 + row;
            float4 v0 = {0.f, 0.f, 0.f, 0.f};
            float4 v1 = {0.f, 0.f, 0.f, 0.f};
            if (n < NI) {
                const float4* g = (const float4*)(W + (size_t)n * F_DIM + k0 + skc);
                v0 = g[0];
                v1 = g[1];
            }
            uint4 h;
            h.x = pk_bf16(v0.x, v0.y);
            h.y = pk_bf16(v0.z, v0.w);
            h.z = pk_bf16(v1.x, v1.y);
            h.w = pk_bf16(v1.z, v1.w);
            *(uint4*)&Bl[row * 64 + skc] = h;
        }
        __syncthreads();
#pragma unroll
        for (int kk = 0; kk < 64; kk += 32) {
            const int kb = kk + quad * 8;
            bf16x8 a[4], b[4];
#pragma unroll
            for (int i = 0; i < 4; ++i)
                a[i] = *(const bf16x8*)&Al[(wm + i * 16 + l16) * 64 + kb];
#pragma unroll
            for (int j = 0; j < 4; ++j)
                b[j] = *(const bf16x8*)&Bl[(wn + j * 16 + l16) * 64 + kb];
#pragma unroll
            for (int i = 0; i < 4; ++i)
#pragma unroll
                for (int j = 0; j < 4; ++j)
                    acc[i][j] = __builtin_amdgcn_mfma_f32_16x16x32_bf16(a[i], b[j], acc[i][j], 0, 0, 0);
        }
        __syncthreads();
    }

    float* dst = part + (size_t)blockIdx.z * (B_DIM * NL);
#pragma unroll
    for (int i = 0; i < 4; ++i) {
        const int mbase = m0 + wm + i * 16 + quad * 4;
#pragma unroll
        for (int j = 0; j < 4; ++j) {
            const int n = n0 + wn + j * 16 + l16;
#pragma unroll
            for (int r = 0; r < 4; ++r)
                dst[(size_t)(mbase + r) * NL + n] = acc[i][j][r];
        }
    }
}

// ---------------- fused reduce + bias + sigmoid + tree ----------------
// 4 waves/block, 1 batch row per wave. grid = B_DIM/4.
__global__ __launch_bounds__(256) void reduce_tree_kernel(
    const float* __restrict__ part, const float* __restrict__ bvec,
    unsigned short* __restrict__ leafbf, int S)
{
    __shared__ float bsh[NL];
    __shared__ float prow[4][NL];

    const int tid = threadIdx.x;
    bsh[tid] = (tid < NI) ? bvec[tid] : 0.0f;
    const int t2 = tid + 256;
    bsh[t2] = (t2 < NI) ? bvec[t2] : 0.0f;

    const int wave = tid >> 6;
    const int lane = tid & 63;
    const int row = blockIdx.x * 4 + wave;
    const size_t base = (size_t)row * NL + lane * 8;

    float4 s0 = {0.f, 0.f, 0.f, 0.f};
    float4 s1 = {0.f, 0.f, 0.f, 0.f};
    for (int s = 0; s < S; ++s) {
        const float4* p = (const float4*)(part + (size_t)s * (B_DIM * NL) + base);
        const float4 a = p[0];
        const float4 b = p[1];
        s0.x += a.x; s0.y += a.y; s0.z += a.z; s0.w += a.w;
        s1.x += b.x; s1.y += b.y; s1.z += b.z; s1.w += b.w;
    }
    __syncthreads();

    float v[8] = {s0.x, s0.y, s0.z, s0.w, s1.x, s1.y, s1.z, s1.w};
#pragma unroll
    for (int i = 0; i < 8; ++i) {
        const float x = v[i] + bsh[lane * 8 + i];
        prow[wave][lane * 8 + i] = 1.0f / (1.0f + __expf(-x));
    }
    __syncthreads();

    const float* pr = prow[wave];
    float pre = 1.0f;
    int pnode = 0;
#pragma unroll
    for (int t = 5; t >= 0; --t) {
        const int bit = (lane >> t) & 1;
        const float p = pr[pnode];
        pre *= bit ? p : (1.0f - p);
        pnode = 2 * pnode + 1 + bit;
    }
    unsigned short outs[8];
#pragma unroll
    for (int jj = 0; jj < 8; ++jj) {
        float prob = pre;
        int node = pnode;
#pragma unroll
        for (int t = 2; t >= 0; --t) {
            const int bit = (jj >> t) & 1;
            const float p = pr[node];
            prob *= bit ? p : (1.0f - p);
            node = 2 * node + 1 + bit;
        }
        outs[jj] = f2bf(prob);
    }
    uint4 r;
    r.x = (unsigned int)outs[0] | ((unsigned int)outs[1] << 16);
    r.y = (unsigned int)outs[2] | ((unsigned int)outs[3] << 16);
    r.z = (unsigned int)outs[4] | ((unsigned int)outs[5] << 16);
    r.w = (unsigned int)outs[6] | ((unsigned int)outs[7] << 16);
    *(uint4*)(leafbf + (size_t)row * NL + lane * 8) = r;
}

// ---------------- softmax + transpose: dT[n][k] = softmax(leaf_params[k])[n] ----------------
__device__ inline float waveMax(float v) {
#pragma unroll
    for (int off = 32; off; off >>= 1) v = fmaxf(v, __shfl_down(v, off, 64));
    return v;
}
__device__ inline float waveSum(float v) {
#pragma unroll
    for (int off = 32; off; off >>= 1) v += __shfl_down(v, off, 64);
    return v;
}

__global__ __launch_bounds__(256) void softmax_transpose_kernel(
    const float* __restrict__ lp, unsigned short* __restrict__ dT)
{
    __shared__ float sred[8];
    const int k = blockIdx.x;   // leaf index 0..511
    const int tid = threadIdx.x;
    const int lane = tid & 63;
    const int wave = tid >> 6;
    const float* rowp = lp + (size_t)k * K_DIM;

    float vals[4];
    float mx = -3.0e38f;
#pragma unroll
    for (int c = 0; c < 4; ++c) {
        const int n = tid + c * 256;
        vals[c] = (n < K_DIM) ? rowp[n] : -3.0e38f;
        mx = fmaxf(mx, vals[c]);
    }
    mx = waveMax(mx);
    if (lane == 0) sred[wave] = mx;
    __syncthreads();
    const float gmax = fmaxf(fmaxf(sred[0], sred[1]), fmaxf(sred[2], sred[3]));

    float sum = 0.f;
#pragma unroll
    for (int c = 0; c < 4; ++c) {
        const int n = tid + c * 256;
        const float e = (n < K_DIM) ? __expf(vals[c] - gmax) : 0.f;
        vals[c] = e;
        sum += e;
    }
    sum = waveSum(sum);
    if (lane == 0) sred[4 + wave] = sum;
    __syncthreads();
    const float inv = 1.0f / (sred[4] + sred[5] + sred[6] + sred[7]);
#pragma unroll
    for (int c = 0; c < 4; ++c) {
        const int n = tid + c * 256;
        if (n < K_DIM) dT[(size_t)n * NL + k] = f2bf(vals[c] * inv);
    }
}

// ---------------- GEMM2: out = leaf_prob @ dists ----------------
// Tile 128M x 64N, BK=64, 4 waves (each 32Mx64N). grid = (16, 64) = 1024 blocks.
__global__ __launch_bounds__(256) void gemm2_kernel(
    const unsigned short* __restrict__ A, const unsigned short* __restrict__ Bm,
    float* __restrict__ out)
{
    __shared__ __align__(16) unsigned short Al[128 * 64];
    __shared__ __align__(16) unsigned short Bl[64 * 64];

    const int tid = threadIdx.x;
    const int m0 = blockIdx.y * 128;
    const int n0 = blockIdx.x * 64;

    const int lane = tid & 63;
    const int wave = tid >> 6;
    const int wm = wave * 32;
    const int quad = lane >> 4;
    const int l16 = lane & 15;

    const f32x4 zero = {0.f, 0.f, 0.f, 0.f};
    f32x4 acc[2][4];
#pragma unroll
    for (int i = 0; i < 2; ++i)
#pragma unroll
        for (int j = 0; j < 4; ++j) acc[i][j] = zero;

    for (int k0 = 0; k0 < NL; k0 += 64) {
#pragma unroll
        for (int w = 0; w < 4; ++w) {
            const int c = w * 256 + tid;
            const int row = c >> 3;
            const int kc = (c & 7) * 8;
            *(uint4*)&Al[row * 64 + kc] =
                *(const uint4*)(A + (size_t)(m0 + row) * NL + k0 + kc);
        }
#pragma unroll
        for (int w = 0; w < 2; ++w) {
            const int c = w * 256 + tid;
            const int row = c >> 3;
            const int kc = (c & 7) * 8;
            *(uint4*)&Bl[row * 64 + kc] =
                *(const uint4*)(Bm + (size_t)(n0 + row) * NL + k0 + kc);
        }
        __syncthreads();
#pragma unroll
        for (int kk = 0; kk < 64; kk += 32) {
            const int kb = kk + quad * 8;
            bf16x8 a[2], b[4];
#pragma unroll
            for (int i = 0; i < 2; ++i)
                a[i] = *(const bf16x8*)&Al[(wm + i * 16 + l16) * 64 + kb];
#pragma unroll
            for (int j = 0; j < 4; ++j)
                b[j] = *(const bf16x8*)&Bl[(j * 16 + l16) * 64 + kb];
#pragma unroll
            for (int i = 0; i < 2; ++i)
#pragma unroll
                for (int j = 0; j < 4; ++j)
                    acc[i][j] = __builtin_amdgcn_mfma_f32_16x16x32_bf16(a[i], b[j], acc[i][j], 0, 0, 0);
        }
        __syncthreads();
    }

#pragma unroll
    for (int i = 0; i < 2; ++i) {
        const int mbase = m0 + wm + i * 16 + quad * 4;
#pragma unroll
        for (int j = 0; j < 4; ++j) {
            const int n = n0 + j * 16 + l16;
            if (n < K_DIM) {
#pragma unroll
                for (int r = 0; r < 4; ++r)
                    out[(size_t)(mbase + r) * K_DIM + n] = acc[i][j][r];
            }
        }
    }
}

extern "C" void kernel_launch(void* const* d_in, const int* in_sizes, int n_in,
                              void* d_out, int out_size, void* d_ws, size_t ws_size,
                              hipStream_t stream) {
    const float* xs = (const float*)d_in[0];
    const float* W  = (const float*)d_in[1];
    const float* b  = (const float*)d_in[2];
    const float* lp = (const float*)d_in[3];
    float* out = (float*)d_out;

    const size_t partBytes = (size_t)B_DIM * NL * 4;   // 16 MB per k-slice
    const size_t leafBytes = (size_t)B_DIM * NL * 2;   // 8 MB
    const size_t dTBytes   = (size_t)KPAD * NL * 2;    // 1 MB

    int S = 1;
    if (ws_size >= 4 * partBytes + leafBytes + dTBytes)      S = 4;
    else if (ws_size >= 2 * partBytes + leafBytes + dTBytes) S = 2;

    char* ws = (char*)d_ws;
    float* part = (float*)ws;
    unsigned short* leafbf = (unsigned short*)(ws + (size_t)S * partBytes);
    unsigned short* dT = (unsigned short*)(ws + (size_t)S * partBytes + leafBytes);

    hipLaunchKernelGGL(gemm1_kernel, dim3(NL / 128, B_DIM / 128, S), dim3(256), 0, stream,
                       xs, W, part, F_DIM / S);
    hipLaunchKernelGGL(softmax_transpose_kernel, dim3(NL), dim3(256), 0, stream, lp, dT);
    hipLaunchKernelGGL(reduce_tree_kernel, dim3(B_DIM / 4), dim3(256), 0, stream,
                       part, b, leafbf, S);
    hipLaunchKernelGGL(gemm2_kernel, dim3(KPAD / 64, B_DIM / 128), dim3(256), 0, stream,
                       leafbf, dT, out);
}

// Round 4
// 334.463 us; speedup vs baseline: 1.5643x; 1.2182x over previous
//
#include <hip/hip_runtime.h>
#include <hip/hip_bf16.h>

// SoftDecisionTree pipeline (R3):
//   xsb  = bf16(xs), Wb = bf16(W) padded    convert kernels (one-time, ws)
//   part = xsb @ Wb^T (split-K)             gemm1_bf16_kernel (global_load_lds staging)
//   lf   = tree(sigmoid(sum_s part + b))    reduce_tree_kernel
//   dT   = softmax(leaf_params)^T (bf16)    softmax_transpose_kernel
//   out  = lf @ dT^T                        gemm2_kernel (global_load_lds staging)

typedef __bf16 bf16x8 __attribute__((ext_vector_type(8)));
typedef float f32x4 __attribute__((ext_vector_type(4)));

#define B_DIM 8192
#define F_DIM 4096
#define NI 511
#define NL 512
#define K_DIM 1000
#define KPAD 1024

// round-to-nearest-even fp32 -> bf16 (bit pattern in low 16)
__device__ inline unsigned short f2bf(float f) {
    unsigned int u = __float_as_uint(f);
    return (unsigned short)((u + 0x7FFFu + ((u >> 16) & 1u)) >> 16);
}

__device__ inline unsigned int pk_bf16(float a, float b) {
    return (unsigned int)f2bf(a) | ((unsigned int)f2bf(b) << 16);
}

// async global->LDS, 16 bytes per lane; LDS dest = wave-uniform base + lane*16
typedef __attribute__((address_space(1))) const unsigned int guint;
typedef __attribute__((address_space(3))) unsigned int luint;
__device__ inline void gload16(const unsigned short* g, unsigned short* l) {
    __builtin_amdgcn_global_load_lds((guint*)g, (luint*)l, 16, 0, 0);
}

// ---------------- converts ----------------
__global__ __launch_bounds__(256) void convert_xs_kernel(
    const float* __restrict__ x, unsigned short* __restrict__ y)
{
    const size_t i = ((size_t)blockIdx.x * 256 + threadIdx.x) * 8;
    const float4 a = *(const float4*)(x + i);
    const float4 b = *(const float4*)(x + i + 4);
    uint4 h;
    h.x = pk_bf16(a.x, a.y);
    h.y = pk_bf16(a.z, a.w);
    h.z = pk_bf16(b.x, b.y);
    h.w = pk_bf16(b.z, b.w);
    *(uint4*)(y + i) = h;
}

// W (511 x 4096 fp32) -> Wb (512 x 4096 bf16, row 511 zeroed)
__global__ __launch_bounds__(256) void convert_w_kernel(
    const float* __restrict__ W, unsigned short* __restrict__ Wb)
{
    const size_t i = ((size_t)blockIdx.x * 256 + threadIdx.x) * 8;
    const int row = (int)(i >> 12);  // /4096
    uint4 h = {0u, 0u, 0u, 0u};
    if (row < NI) {
        const float4 a = *(const float4*)(W + i);
        const float4 b = *(const float4*)(W + i + 4);
        h.x = pk_bf16(a.x, a.y);
        h.y = pk_bf16(a.z, a.w);
        h.z = pk_bf16(b.x, b.y);
        h.w = pk_bf16(b.z, b.w);
    }
    *(uint4*)(Wb + i) = h;
}

// ---------------- GEMM1 (split-K, bf16 in, global_load_lds staging) ----------------
// part[z] = xsb @ Wb^T over k-slice z. Tile 128x128, BK=64, 4 waves.
__global__ __launch_bounds__(256) void gemm1_bf16_kernel(
    const unsigned short* __restrict__ Ab, const unsigned short* __restrict__ Bb,
    float* __restrict__ part, int kchunk)
{
    __shared__ __align__(16) unsigned short Al[128 * 64];
    __shared__ __align__(16) unsigned short Bl[128 * 64];

    const int tid = threadIdx.x;
    const int m0 = blockIdx.y * 128;
    const int n0 = blockIdx.x * 128;
    const int kbeg = blockIdx.z * kchunk;
    const int kend = kbeg + kchunk;

    const int lane = tid & 63;
    const int wave = tid >> 6;
    const int wm = (wave >> 1) * 64;
    const int wn = (wave & 1) * 64;
    const int quad = lane >> 4;
    const int l16 = lane & 15;

    // staging: seg = pass*4 + wave covers rows seg*8..seg*8+7 (1 KiB per wave-segment)
    const int srow8 = lane >> 3;        // row within segment
    const int scol  = (lane & 7) * 8;   // element col within row
    const unsigned short* gA = Ab + (size_t)(m0 + wave * 8 + srow8) * F_DIM + scol;
    const unsigned short* gB = Bb + (size_t)(n0 + wave * 8 + srow8) * F_DIM + scol;
    unsigned short* lA = &Al[wave * 8 * 64];
    unsigned short* lB = &Bl[wave * 8 * 64];

    const f32x4 zero = {0.f, 0.f, 0.f, 0.f};
    f32x4 acc[4][4];
#pragma unroll
    for (int i = 0; i < 4; ++i)
#pragma unroll
        for (int j = 0; j < 4; ++j) acc[i][j] = zero;

    for (int k0 = kbeg; k0 < kend; k0 += 64) {
        const unsigned short* a = gA + k0;
        const unsigned short* b = gB + k0;
#pragma unroll
        for (int p = 0; p < 4; ++p) {
            gload16(a + (size_t)p * 32 * F_DIM, lA + p * 2048);
            gload16(b + (size_t)p * 32 * F_DIM, lB + p * 2048);
        }
        __syncthreads();
#pragma unroll
        for (int kk = 0; kk < 64; kk += 32) {
            const int kb = kk + quad * 8;
            bf16x8 av[4], bv[4];
#pragma unroll
            for (int i = 0; i < 4; ++i)
                av[i] = *(const bf16x8*)&Al[(wm + i * 16 + l16) * 64 + kb];
#pragma unroll
            for (int j = 0; j < 4; ++j)
                bv[j] = *(const bf16x8*)&Bl[(wn + j * 16 + l16) * 64 + kb];
#pragma unroll
            for (int i = 0; i < 4; ++i)
#pragma unroll
                for (int j = 0; j < 4; ++j)
                    acc[i][j] = __builtin_amdgcn_mfma_f32_16x16x32_bf16(av[i], bv[j], acc[i][j], 0, 0, 0);
        }
        __syncthreads();
    }

    float* dst = part + (size_t)blockIdx.z * (B_DIM * NL);
#pragma unroll
    for (int i = 0; i < 4; ++i) {
        const int mbase = m0 + wm + i * 16 + quad * 4;
#pragma unroll
        for (int j = 0; j < 4; ++j) {
            const int n = n0 + wn + j * 16 + l16;
#pragma unroll
            for (int r = 0; r < 4; ++r)
                dst[(size_t)(mbase + r) * NL + n] = acc[i][j][r];
        }
    }
}

// ---------------- GEMM1 fallback (fp32 in-kernel cvt staging, R2 path) ----------------
__global__ __launch_bounds__(256) void gemm1_fp32_kernel(
    const float* __restrict__ xs, const float* __restrict__ W,
    float* __restrict__ part, int kchunk)
{
    __shared__ __align__(16) unsigned short Al[128 * 64];
    __shared__ __align__(16) unsigned short Bl[128 * 64];

    const int tid = threadIdx.x;
    const int m0 = blockIdx.y * 128;
    const int n0 = blockIdx.x * 128;
    const int kbeg = blockIdx.z * kchunk;
    const int kend = kbeg + kchunk;

    const int lane = tid & 63;
    const int wave = tid >> 6;
    const int wm = (wave >> 1) * 64;
    const int wn = (wave & 1) * 64;
    const int quad = lane >> 4;
    const int l16 = lane & 15;

    const int srow = tid >> 3;
    const int skc  = (tid & 7) * 8;

    const f32x4 zero = {0.f, 0.f, 0.f, 0.f};
    f32x4 acc[4][4];
#pragma unroll
    for (int i = 0; i < 4; ++i)
#pragma unroll
        for (int j = 0; j < 4; ++j) acc[i][j] = zero;

    for (int k0 = kbeg; k0 < kend; k0 += 64) {
#pragma unroll
        for (int w = 0; w < 4; ++w) {
            const int row = w * 32 + srow;
            const float4* g = (const float4*)(xs + (size_t)(m0 + row) * F_DIM + k0 + skc);
            const float4 v0 = g[0];
            const float4 v1 = g[1];
            uint4 h;
            h.x = pk_bf16(v0.x, v0.y);
            h.y = pk_bf16(v0.z, v0.w);
            h.z = pk_bf16(v1.x, v1.y);
            h.w = pk_bf16(v1.z, v1.w);
            *(uint4*)&Al[row * 64 + skc] = h;
        }
#pragma unroll
        for (int w = 0; w < 4; ++w) {
            const int row = w * 32 + srow;
            const int n = n0 + row;
            float4 v0 = {0.f, 0.f, 0.f, 0.f};
            float4 v1 = {0.f, 0.f, 0.f, 0.f};
            if (n < NI) {
                const float4* g = (const float4*)(W + (size_t)n * F_DIM + k0 + skc);
                v0 = g[0];
                v1 = g[1];
            }
            uint4 h;
            h.x = pk_bf16(v0.x, v0.y);
            h.y = pk_bf16(v0.z, v0.w);
            h.z = pk_bf16(v1.x, v1.y);
            h.w = pk_bf16(v1.z, v1.w);
            *(uint4*)&Bl[row * 64 + skc] = h;
        }
        __syncthreads();
#pragma unroll
        for (int kk = 0; kk < 64; kk += 32) {
            const int kb = kk + quad * 8;
            bf16x8 a[4], b[4];
#pragma unroll
            for (int i = 0; i < 4; ++i)
                a[i] = *(const bf16x8*)&Al[(wm + i * 16 + l16) * 64 + kb];
#pragma unroll
            for (int j = 0; j < 4; ++j)
                b[j] = *(const bf16x8*)&Bl[(wn + j * 16 + l16) * 64 + kb];
#pragma unroll
            for (int i = 0; i < 4; ++i)
#pragma unroll
                for (int j = 0; j < 4; ++j)
                    acc[i][j] = __builtin_amdgcn_mfma_f32_16x16x32_bf16(a[i], b[j], acc[i][j], 0, 0, 0);
        }
        __syncthreads();
    }

    float* dst = part + (size_t)blockIdx.z * (B_DIM * NL);
#pragma unroll
    for (int i = 0; i < 4; ++i) {
        const int mbase = m0 + wm + i * 16 + quad * 4;
#pragma unroll
        for (int j = 0; j < 4; ++j) {
            const int n = n0 + wn + j * 16 + l16;
#pragma unroll
            for (int r = 0; r < 4; ++r)
                dst[(size_t)(mbase + r) * NL + n] = acc[i][j][r];
        }
    }
}

// ---------------- fused reduce + bias + sigmoid + tree ----------------
__global__ __launch_bounds__(256) void reduce_tree_kernel(
    const float* __restrict__ part, const float* __restrict__ bvec,
    unsigned short* __restrict__ leafbf, int S)
{
    __shared__ float bsh[NL];
    __shared__ float prow[4][NL];

    const int tid = threadIdx.x;
    bsh[tid] = (tid < NI) ? bvec[tid] : 0.0f;
    const int t2 = tid + 256;
    bsh[t2] = (t2 < NI) ? bvec[t2] : 0.0f;

    const int wave = tid >> 6;
    const int lane = tid & 63;
    const int row = blockIdx.x * 4 + wave;
    const size_t base = (size_t)row * NL + lane * 8;

    float4 s0 = {0.f, 0.f, 0.f, 0.f};
    float4 s1 = {0.f, 0.f, 0.f, 0.f};
    for (int s = 0; s < S; ++s) {
        const float4* p = (const float4*)(part + (size_t)s * (B_DIM * NL) + base);
        const float4 a = p[0];
        const float4 b = p[1];
        s0.x += a.x; s0.y += a.y; s0.z += a.z; s0.w += a.w;
        s1.x += b.x; s1.y += b.y; s1.z += b.z; s1.w += b.w;
    }
    __syncthreads();

    float v[8] = {s0.x, s0.y, s0.z, s0.w, s1.x, s1.y, s1.z, s1.w};
#pragma unroll
    for (int i = 0; i < 8; ++i) {
        const float x = v[i] + bsh[lane * 8 + i];
        prow[wave][lane * 8 + i] = 1.0f / (1.0f + __expf(-x));
    }
    __syncthreads();

    const float* pr = prow[wave];
    float pre = 1.0f;
    int pnode = 0;
#pragma unroll
    for (int t = 5; t >= 0; --t) {
        const int bit = (lane >> t) & 1;
        const float p = pr[pnode];
        pre *= bit ? p : (1.0f - p);
        pnode = 2 * pnode + 1 + bit;
    }
    unsigned short outs[8];
#pragma unroll
    for (int jj = 0; jj < 8; ++jj) {
        float prob = pre;
        int node = pnode;
#pragma unroll
        for (int t = 2; t >= 0; --t) {
            const int bit = (jj >> t) & 1;
            const float p = pr[node];
            prob *= bit ? p : (1.0f - p);
            node = 2 * node + 1 + bit;
        }
        outs[jj] = f2bf(prob);
    }
    uint4 r;
    r.x = (unsigned int)outs[0] | ((unsigned int)outs[1] << 16);
    r.y = (unsigned int)outs[2] | ((unsigned int)outs[3] << 16);
    r.z = (unsigned int)outs[4] | ((unsigned int)outs[5] << 16);
    r.w = (unsigned int)outs[6] | ((unsigned int)outs[7] << 16);
    *(uint4*)(leafbf + (size_t)row * NL + lane * 8) = r;
}

// ---------------- softmax + transpose ----------------
__device__ inline float waveMax(float v) {
#pragma unroll
    for (int off = 32; off; off >>= 1) v = fmaxf(v, __shfl_down(v, off, 64));
    return v;
}
__device__ inline float waveSum(float v) {
#pragma unroll
    for (int off = 32; off; off >>= 1) v += __shfl_down(v, off, 64);
    return v;
}

__global__ __launch_bounds__(256) void softmax_transpose_kernel(
    const float* __restrict__ lp, unsigned short* __restrict__ dT)
{
    __shared__ float sred[8];
    const int k = blockIdx.x;
    const int tid = threadIdx.x;
    const int lane = tid & 63;
    const int wave = tid >> 6;
    const float* rowp = lp + (size_t)k * K_DIM;

    float vals[4];
    float mx = -3.0e38f;
#pragma unroll
    for (int c = 0; c < 4; ++c) {
        const int n = tid + c * 256;
        vals[c] = (n < K_DIM) ? rowp[n] : -3.0e38f;
        mx = fmaxf(mx, vals[c]);
    }
    mx = waveMax(mx);
    if (lane == 0) sred[wave] = mx;
    __syncthreads();
    const float gmax = fmaxf(fmaxf(sred[0], sred[1]), fmaxf(sred[2], sred[3]));

    float sum = 0.f;
#pragma unroll
    for (int c = 0; c < 4; ++c) {
        const int n = tid + c * 256;
        const float e = (n < K_DIM) ? __expf(vals[c] - gmax) : 0.f;
        vals[c] = e;
        sum += e;
    }
    sum = waveSum(sum);
    if (lane == 0) sred[4 + wave] = sum;
    __syncthreads();
    const float inv = 1.0f / (sred[4] + sred[5] + sred[6] + sred[7]);
#pragma unroll
    for (int c = 0; c < 4; ++c) {
        const int n = tid + c * 256;
        if (n < K_DIM) dT[(size_t)n * NL + k] = f2bf(vals[c] * inv);
    }
}

// ---------------- GEMM2: out = leaf_prob @ dists (global_load_lds staging) ----------------
// Tile 128x128, BK=64, K=512. grid (KPAD/128=8, B_DIM/128=64) = 512 blocks.
__global__ __launch_bounds__(256) void gemm2_kernel(
    const unsigned short* __restrict__ A, const unsigned short* __restrict__ Bm,
    float* __restrict__ out)
{
    __shared__ __align__(16) unsigned short Al[128 * 64];
    __shared__ __align__(16) unsigned short Bl[128 * 64];

    const int tid = threadIdx.x;
    const int m0 = blockIdx.y * 128;
    const int n0 = blockIdx.x * 128;

    const int lane = tid & 63;
    const int wave = tid >> 6;
    const int wm = (wave >> 1) * 64;
    const int wn = (wave & 1) * 64;
    const int quad = lane >> 4;
    const int l16 = lane & 15;

    const int srow8 = lane >> 3;
    const int scol  = (lane & 7) * 8;
    const unsigned short* gA = A + (size_t)(m0 + wave * 8 + srow8) * NL + scol;
    const unsigned short* gB = Bm + (size_t)(n0 + wave * 8 + srow8) * NL + scol;
    unsigned short* lA = &Al[wave * 8 * 64];
    unsigned short* lB = &Bl[wave * 8 * 64];

    const f32x4 zero = {0.f, 0.f, 0.f, 0.f};
    f32x4 acc[4][4];
#pragma unroll
    for (int i = 0; i < 4; ++i)
#pragma unroll
        for (int j = 0; j < 4; ++j) acc[i][j] = zero;

    for (int k0 = 0; k0 < NL; k0 += 64) {
        const unsigned short* a = gA + k0;
        const unsigned short* b = gB + k0;
#pragma unroll
        for (int p = 0; p < 4; ++p) {
            gload16(a + (size_t)p * 32 * NL, lA + p * 2048);
            gload16(b + (size_t)p * 32 * NL, lB + p * 2048);
        }
        __syncthreads();
#pragma unroll
        for (int kk = 0; kk < 64; kk += 32) {
            const int kb = kk + quad * 8;
            bf16x8 av[4], bv[4];
#pragma unroll
            for (int i = 0; i < 4; ++i)
                av[i] = *(const bf16x8*)&Al[(wm + i * 16 + l16) * 64 + kb];
#pragma unroll
            for (int j = 0; j < 4; ++j)
                bv[j] = *(const bf16x8*)&Bl[(wn + j * 16 + l16) * 64 + kb];
#pragma unroll
            for (int i = 0; i < 4; ++i)
#pragma unroll
                for (int j = 0; j < 4; ++j)
                    acc[i][j] = __builtin_amdgcn_mfma_f32_16x16x32_bf16(av[i], bv[j], acc[i][j], 0, 0, 0);
        }
        __syncthreads();
    }

#pragma unroll
    for (int i = 0; i < 4; ++i) {
        const int mbase = m0 + wm + i * 16 + quad * 4;
#pragma unroll
        for (int j = 0; j < 4; ++j) {
            const int n = n0 + wn + j * 16 + l16;
            if (n < K_DIM) {
#pragma unroll
                for (int r = 0; r < 4; ++r)
                    out[(size_t)(mbase + r) * K_DIM + n] = acc[i][j][r];
            }
        }
    }
}

extern "C" void kernel_launch(void* const* d_in, const int* in_sizes, int n_in,
                              void* d_out, int out_size, void* d_ws, size_t ws_size,
                              hipStream_t stream) {
    const float* xs = (const float*)d_in[0];
    const float* W  = (const float*)d_in[1];
    const float* b  = (const float*)d_in[2];
    const float* lp = (const float*)d_in[3];
    float* out = (float*)d_out;

    const size_t xsbB  = (size_t)B_DIM * F_DIM * 2;  // 64 MiB
    const size_t WbB   = (size_t)NL * F_DIM * 2;     //  4 MiB
    const size_t partB = (size_t)B_DIM * NL * 4;     // 16 MiB per slice
    const size_t leafB = (size_t)B_DIM * NL * 2;     //  8 MiB
    const size_t dTB   = (size_t)KPAD * NL * 2;      //  1 MiB

    char* ws = (char*)d_ws;

    // preferred path: pre-converted bf16 inputs + global_load_lds GEMM1
    int S = 0;
    if      (ws_size >= xsbB + WbB + 4 * partB + leafB + dTB) S = 4;
    else if (ws_size >= xsbB + WbB + 2 * partB + leafB + dTB) S = 2;
    else if (ws_size >= xsbB + WbB + 1 * partB + leafB + dTB) S = 1;

    if (S > 0) {
        unsigned short* xsb = (unsigned short*)ws;
        unsigned short* Wb  = (unsigned short*)(ws + xsbB);
        float* part = (float*)(ws + xsbB + WbB);
        unsigned short* leafbf = (unsigned short*)(ws + xsbB + WbB + (size_t)S * partB);
        unsigned short* dT = (unsigned short*)(ws + xsbB + WbB + (size_t)S * partB + leafB);

        hipLaunchKernelGGL(convert_w_kernel, dim3((NL * F_DIM) / (256 * 8)), dim3(256), 0, stream, W, Wb);
        hipLaunchKernelGGL(convert_xs_kernel, dim3((B_DIM * F_DIM) / (256 * 8)), dim3(256), 0, stream, xs, xsb);
        hipLaunchKernelGGL(gemm1_bf16_kernel, dim3(NL / 128, B_DIM / 128, S), dim3(256), 0, stream,
                           xsb, Wb, part, F_DIM / S);
        hipLaunchKernelGGL(softmax_transpose_kernel, dim3(NL), dim3(256), 0, stream, lp, dT);
        hipLaunchKernelGGL(reduce_tree_kernel, dim3(B_DIM / 4), dim3(256), 0, stream,
                           part, b, leafbf, S);
        hipLaunchKernelGGL(gemm2_kernel, dim3(KPAD / 128, B_DIM / 128), dim3(256), 0, stream,
                           leafbf, dT, out);
    } else {
        // fallback: R2 path (fp32 staging GEMM1)
        int S2 = 1;
        if      (ws_size >= 4 * partB + leafB + dTB) S2 = 4;
        else if (ws_size >= 2 * partB + leafB + dTB) S2 = 2;
        float* part = (float*)ws;
        unsigned short* leafbf = (unsigned short*)(ws + (size_t)S2 * partB);
        unsigned short* dT = (unsigned short*)(ws + (size_t)S2 * partB + leafB);

        hipLaunchKernelGGL(gemm1_fp32_kernel, dim3(NL / 128, B_DIM / 128, S2), dim3(256), 0, stream,
                           xs, W, part, F_DIM / S2);
        hipLaunchKernelGGL(softmax_transpose_kernel, dim3(NL), dim3(256), 0, stream, lp, dT);
        hipLaunchKernelGGL(reduce_tree_kernel, dim3(B_DIM / 4), dim3(256), 0, stream,
                           part, b, leafbf, S2);
        hipLaunchKernelGGL(gemm2_kernel, dim3(KPAD / 128, B_DIM / 128), dim3(256), 0, stream,
                           leafbf, dT, out);
    }
}

// Round 5
// 305.263 us; speedup vs baseline: 1.7139x; 1.0957x over previous
//
#include <hip/hip_runtime.h>
#include <hip/hip_bf16.h>

// SoftDecisionTree pipeline (R5: XCD-swizzled GEMMs, fused prep):
//   prep : xsb=bf16(xs), Wb=bf16(W) padded, dT=softmax(leaf_params)^T   (1 kernel)
//   part = xsb @ Wb^T (split-K, XCD-swizzled)                            gemm1_bf16_kernel
//   lf   = tree(sigmoid(sum_s part + b))                                 reduce_tree_kernel
//   out  = lf @ dT^T (XCD-swizzled)                                      gemm2_kernel

typedef __bf16 bf16x8 __attribute__((ext_vector_type(8)));
typedef float f32x4 __attribute__((ext_vector_type(4)));

#define B_DIM 8192
#define F_DIM 4096
#define NI 511
#define NL 512
#define K_DIM 1000
#define KPAD 1024

#define XS_BLKS 16384   // 8192*4096 / (256*8)
#define W_BLKS  1024    // 512*4096 / (256*8)
#define SM_BLKS 512

// round-to-nearest-even fp32 -> bf16
__device__ inline unsigned short f2bf(float f) {
    unsigned int u = __float_as_uint(f);
    return (unsigned short)((u + 0x7FFFu + ((u >> 16) & 1u)) >> 16);
}
__device__ inline unsigned int pk_bf16(float a, float b) {
    return (unsigned int)f2bf(a) | ((unsigned int)f2bf(b) << 16);
}

// async global->LDS, 16 B/lane; LDS dest = wave-uniform base + lane*16
typedef __attribute__((address_space(1))) const unsigned int guint;
typedef __attribute__((address_space(3))) unsigned int luint;
__device__ inline void gload16(const unsigned short* g, unsigned short* l) {
    __builtin_amdgcn_global_load_lds((guint*)g, (luint*)l, 16, 0, 0);
}

__device__ inline float waveMax(float v) {
#pragma unroll
    for (int off = 32; off; off >>= 1) v = fmaxf(v, __shfl_down(v, off, 64));
    return v;
}
__device__ inline float waveSum(float v) {
#pragma unroll
    for (int off = 32; off; off >>= 1) v += __shfl_down(v, off, 64);
    return v;
}

// ---------------- fused prep: xs->bf16, W->bf16 (padded), softmax^T ----------------
__global__ __launch_bounds__(256) void prep_kernel(
    const float* __restrict__ xs, unsigned short* __restrict__ xsb,
    const float* __restrict__ W, unsigned short* __restrict__ Wb,
    const float* __restrict__ lp, unsigned short* __restrict__ dT)
{
    __shared__ float sred[8];
    const int bid = blockIdx.x;
    const int tid = threadIdx.x;

    if (bid < XS_BLKS) {
        const size_t i = ((size_t)bid * 256 + tid) * 8;
        const float4 a = *(const float4*)(xs + i);
        const float4 b = *(const float4*)(xs + i + 4);
        uint4 h;
        h.x = pk_bf16(a.x, a.y);
        h.y = pk_bf16(a.z, a.w);
        h.z = pk_bf16(b.x, b.y);
        h.w = pk_bf16(b.z, b.w);
        *(uint4*)(xsb + i) = h;
        return;
    }
    if (bid < XS_BLKS + W_BLKS) {
        const size_t i = ((size_t)(bid - XS_BLKS) * 256 + tid) * 8;
        const int row = (int)(i >> 12);  // /4096
        uint4 h = {0u, 0u, 0u, 0u};
        if (row < NI) {
            const float4 a = *(const float4*)(W + i);
            const float4 b = *(const float4*)(W + i + 4);
            h.x = pk_bf16(a.x, a.y);
            h.y = pk_bf16(a.z, a.w);
            h.z = pk_bf16(b.x, b.y);
            h.w = pk_bf16(b.z, b.w);
        }
        *(uint4*)(Wb + i) = h;
        return;
    }
    // softmax + transpose: dT[n][k] = softmax(leaf_params[k])[n]
    const int k = bid - (XS_BLKS + W_BLKS);
    const int lane = tid & 63;
    const int wave = tid >> 6;
    const float* rowp = lp + (size_t)k * K_DIM;

    float vals[4];
    float mx = -3.0e38f;
#pragma unroll
    for (int c = 0; c < 4; ++c) {
        const int n = tid + c * 256;
        vals[c] = (n < K_DIM) ? rowp[n] : -3.0e38f;
        mx = fmaxf(mx, vals[c]);
    }
    mx = waveMax(mx);
    if (lane == 0) sred[wave] = mx;
    __syncthreads();
    const float gmax = fmaxf(fmaxf(sred[0], sred[1]), fmaxf(sred[2], sred[3]));

    float sum = 0.f;
#pragma unroll
    for (int c = 0; c < 4; ++c) {
        const int n = tid + c * 256;
        const float e = (n < K_DIM) ? __expf(vals[c] - gmax) : 0.f;
        vals[c] = e;
        sum += e;
    }
    sum = waveSum(sum);
    if (lane == 0) sred[4 + wave] = sum;
    __syncthreads();
    const float inv = 1.0f / (sred[4] + sred[5] + sred[6] + sred[7]);
#pragma unroll
    for (int c = 0; c < 4; ++c) {
        const int n = tid + c * 256;
        if (n < K_DIM) dT[(size_t)n * NL + k] = f2bf(vals[c] * inv);
    }
}

// ---------------- GEMM1 (split-K, bf16, global_load_lds, XCD swizzle) ----------------
// 1D grid of 4*64*S blocks. xcd = m&7 so the 4 n-tiles sharing an A-tile land on
// one XCD in adjacent dispatch slots -> A fetched once per XCD, L2-hot loads.
__global__ __launch_bounds__(256) void gemm1_bf16_kernel(
    const unsigned short* __restrict__ Ab, const unsigned short* __restrict__ Bb,
    float* __restrict__ part, int kchunk, int S)
{
    __shared__ __align__(16) unsigned short Al[128 * 64];
    __shared__ __align__(16) unsigned short Bl[128 * 64];

    const int id = blockIdx.x;
    const int xcd = id & 7;
    const int j = id >> 3;
    const int per = 4 * S;            // (z,n) combos per m-group
    const int mhi = j / per;
    const int t = j - mhi * per;
    const int z = t >> 2;
    const int nt = t & 3;
    const int m0 = (mhi * 8 + xcd) * 128;
    const int n0 = nt * 128;
    const int kbeg = z * kchunk;
    const int kend = kbeg + kchunk;

    const int tid = threadIdx.x;
    const int lane = tid & 63;
    const int wave = tid >> 6;
    const int wm = (wave >> 1) * 64;
    const int wn = (wave & 1) * 64;
    const int quad = lane >> 4;
    const int l16 = lane & 15;

    const int srow8 = lane >> 3;
    const int scol  = (lane & 7) * 8;
    const unsigned short* gA = Ab + (size_t)(m0 + wave * 8 + srow8) * F_DIM + scol;
    const unsigned short* gB = Bb + (size_t)(n0 + wave * 8 + srow8) * F_DIM + scol;
    unsigned short* lA = &Al[wave * 8 * 64];
    unsigned short* lB = &Bl[wave * 8 * 64];

    const f32x4 zero = {0.f, 0.f, 0.f, 0.f};
    f32x4 acc[4][4];
#pragma unroll
    for (int i = 0; i < 4; ++i)
#pragma unroll
        for (int j2 = 0; j2 < 4; ++j2) acc[i][j2] = zero;

    for (int k0 = kbeg; k0 < kend; k0 += 64) {
        const unsigned short* a = gA + k0;
        const unsigned short* b = gB + k0;
#pragma unroll
        for (int p = 0; p < 4; ++p) {
            gload16(a + (size_t)p * 32 * F_DIM, lA + p * 2048);
            gload16(b + (size_t)p * 32 * F_DIM, lB + p * 2048);
        }
        __syncthreads();
#pragma unroll
        for (int kk = 0; kk < 64; kk += 32) {
            const int kb = kk + quad * 8;
            bf16x8 av[4], bv[4];
#pragma unroll
            for (int i = 0; i < 4; ++i)
                av[i] = *(const bf16x8*)&Al[(wm + i * 16 + l16) * 64 + kb];
#pragma unroll
            for (int j2 = 0; j2 < 4; ++j2)
                bv[j2] = *(const bf16x8*)&Bl[(wn + j2 * 16 + l16) * 64 + kb];
#pragma unroll
            for (int i = 0; i < 4; ++i)
#pragma unroll
                for (int j2 = 0; j2 < 4; ++j2)
                    acc[i][j2] = __builtin_amdgcn_mfma_f32_16x16x32_bf16(av[i], bv[j2], acc[i][j2], 0, 0, 0);
        }
        __syncthreads();
    }

    float* dst = part + (size_t)z * (B_DIM * NL);
#pragma unroll
    for (int i = 0; i < 4; ++i) {
        const int mbase = m0 + wm + i * 16 + quad * 4;
#pragma unroll
        for (int j2 = 0; j2 < 4; ++j2) {
            const int n = n0 + wn + j2 * 16 + l16;
#pragma unroll
            for (int r = 0; r < 4; ++r)
                dst[(size_t)(mbase + r) * NL + n] = acc[i][j2][r];
        }
    }
}

// ---------------- fused reduce + bias + sigmoid + tree ----------------
__global__ __launch_bounds__(256) void reduce_tree_kernel(
    const float* __restrict__ part, const float* __restrict__ bvec,
    unsigned short* __restrict__ leafbf, int S)
{
    __shared__ float bsh[NL];
    __shared__ float prow[4][NL];

    const int tid = threadIdx.x;
    bsh[tid] = (tid < NI) ? bvec[tid] : 0.0f;
    const int t2 = tid + 256;
    bsh[t2] = (t2 < NI) ? bvec[t2] : 0.0f;

    const int wave = tid >> 6;
    const int lane = tid & 63;
    const int row = blockIdx.x * 4 + wave;
    const size_t base = (size_t)row * NL + lane * 8;

    float4 s0 = {0.f, 0.f, 0.f, 0.f};
    float4 s1 = {0.f, 0.f, 0.f, 0.f};
    for (int s = 0; s < S; ++s) {
        const float4* p = (const float4*)(part + (size_t)s * (B_DIM * NL) + base);
        const float4 a = p[0];
        const float4 b = p[1];
        s0.x += a.x; s0.y += a.y; s0.z += a.z; s0.w += a.w;
        s1.x += b.x; s1.y += b.y; s1.z += b.z; s1.w += b.w;
    }
    __syncthreads();

    float v[8] = {s0.x, s0.y, s0.z, s0.w, s1.x, s1.y, s1.z, s1.w};
#pragma unroll
    for (int i = 0; i < 8; ++i) {
        const float x = v[i] + bsh[lane * 8 + i];
        prow[wave][lane * 8 + i] = 1.0f / (1.0f + __expf(-x));
    }
    __syncthreads();

    const float* pr = prow[wave];
    float pre = 1.0f;
    int pnode = 0;
#pragma unroll
    for (int t = 5; t >= 0; --t) {
        const int bit = (lane >> t) & 1;
        const float p = pr[pnode];
        pre *= bit ? p : (1.0f - p);
        pnode = 2 * pnode + 1 + bit;
    }
    unsigned short outs[8];
#pragma unroll
    for (int jj = 0; jj < 8; ++jj) {
        float prob = pre;
        int node = pnode;
#pragma unroll
        for (int t = 2; t >= 0; --t) {
            const int bit = (jj >> t) & 1;
            const float p = pr[node];
            prob *= bit ? p : (1.0f - p);
            node = 2 * node + 1 + bit;
        }
        outs[jj] = f2bf(prob);
    }
    uint4 r;
    r.x = (unsigned int)outs[0] | ((unsigned int)outs[1] << 16);
    r.y = (unsigned int)outs[2] | ((unsigned int)outs[3] << 16);
    r.z = (unsigned int)outs[4] | ((unsigned int)outs[5] << 16);
    r.w = (unsigned int)outs[6] | ((unsigned int)outs[7] << 16);
    *(uint4*)(leafbf + (size_t)row * NL + lane * 8) = r;
}

// ---------------- GEMM2: out = leaf_prob @ dists (XCD swizzle) ----------------
// 1D grid 512: xcd = m&7; 8 n-tiles sharing an A-tile colocate on one XCD.
__global__ __launch_bounds__(256) void gemm2_kernel(
    const unsigned short* __restrict__ A, const unsigned short* __restrict__ Bm,
    float* __restrict__ out)
{
    __shared__ __align__(16) unsigned short Al[128 * 64];
    __shared__ __align__(16) unsigned short Bl[128 * 64];

    const int id = blockIdx.x;
    const int xcd = id & 7;
    const int j = id >> 3;
    const int nt = j & 7;
    const int mhi = j >> 3;
    const int m0 = (mhi * 8 + xcd) * 128;
    const int n0 = nt * 128;

    const int tid = threadIdx.x;
    const int lane = tid & 63;
    const int wave = tid >> 6;
    const int wm = (wave >> 1) * 64;
    const int wn = (wave & 1) * 64;
    const int quad = lane >> 4;
    const int l16 = lane & 15;

    const int srow8 = lane >> 3;
    const int scol  = (lane & 7) * 8;
    const unsigned short* gA = A + (size_t)(m0 + wave * 8 + srow8) * NL + scol;
    const unsigned short* gB = Bm + (size_t)(n0 + wave * 8 + srow8) * NL + scol;
    unsigned short* lA = &Al[wave * 8 * 64];
    unsigned short* lB = &Bl[wave * 8 * 64];

    const f32x4 zero = {0.f, 0.f, 0.f, 0.f};
    f32x4 acc[4][4];
#pragma unroll
    for (int i = 0; i < 4; ++i)
#pragma unroll
        for (int j2 = 0; j2 < 4; ++j2) acc[i][j2] = zero;

    for (int k0 = 0; k0 < NL; k0 += 64) {
        const unsigned short* a = gA + k0;
        const unsigned short* b = gB + k0;
#pragma unroll
        for (int p = 0; p < 4; ++p) {
            gload16(a + (size_t)p * 32 * NL, lA + p * 2048);
            gload16(b + (size_t)p * 32 * NL, lB + p * 2048);
        }
        __syncthreads();
#pragma unroll
        for (int kk = 0; kk < 64; kk += 32) {
            const int kb = kk + quad * 8;
            bf16x8 av[4], bv[4];
#pragma unroll
            for (int i = 0; i < 4; ++i)
                av[i] = *(const bf16x8*)&Al[(wm + i * 16 + l16) * 64 + kb];
#pragma unroll
            for (int j2 = 0; j2 < 4; ++j2)
                bv[j2] = *(const bf16x8*)&Bl[(wn + j2 * 16 + l16) * 64 + kb];
#pragma unroll
            for (int i = 0; i < 4; ++i)
#pragma unroll
                for (int j2 = 0; j2 < 4; ++j2)
                    acc[i][j2] = __builtin_amdgcn_mfma_f32_16x16x32_bf16(av[i], bv[j2], acc[i][j2], 0, 0, 0);
        }
        __syncthreads();
    }

#pragma unroll
    for (int i = 0; i < 4; ++i) {
        const int mbase = m0 + wm + i * 16 + quad * 4;
#pragma unroll
        for (int j2 = 0; j2 < 4; ++j2) {
            const int n = n0 + wn + j2 * 16 + l16;
            if (n < K_DIM) {
#pragma unroll
                for (int r = 0; r < 4; ++r)
                    out[(size_t)(mbase + r) * K_DIM + n] = acc[i][j2][r];
            }
        }
    }
}

extern "C" void kernel_launch(void* const* d_in, const int* in_sizes, int n_in,
                              void* d_out, int out_size, void* d_ws, size_t ws_size,
                              hipStream_t stream) {
    const float* xs = (const float*)d_in[0];
    const float* W  = (const float*)d_in[1];
    const float* b  = (const float*)d_in[2];
    const float* lp = (const float*)d_in[3];
    float* out = (float*)d_out;

    const size_t xsbB  = (size_t)B_DIM * F_DIM * 2;  // 64 MiB
    const size_t WbB   = (size_t)NL * F_DIM * 2;     //  4 MiB
    const size_t partB = (size_t)B_DIM * NL * 4;     // 16 MiB per slice
    const size_t leafB = (size_t)B_DIM * NL * 2;     //  8 MiB
    const size_t dTB   = (size_t)KPAD * NL * 2;      //  1 MiB

    int S = 1;
    if      (ws_size >= xsbB + WbB + 4 * partB + leafB + dTB) S = 4;
    else if (ws_size >= xsbB + WbB + 2 * partB + leafB + dTB) S = 2;

    char* ws = (char*)d_ws;
    unsigned short* xsb = (unsigned short*)ws;
    unsigned short* Wb  = (unsigned short*)(ws + xsbB);
    float* part = (float*)(ws + xsbB + WbB);
    unsigned short* leafbf = (unsigned short*)(ws + xsbB + WbB + (size_t)S * partB);
    unsigned short* dT = (unsigned short*)(ws + xsbB + WbB + (size_t)S * partB + leafB);

    hipLaunchKernelGGL(prep_kernel, dim3(XS_BLKS + W_BLKS + SM_BLKS), dim3(256), 0, stream,
                       xs, xsb, W, Wb, lp, dT);
    hipLaunchKernelGGL(gemm1_bf16_kernel, dim3(4 * (B_DIM / 128) * S), dim3(256), 0, stream,
                       xsb, Wb, part, F_DIM / S, S);
    hipLaunchKernelGGL(reduce_tree_kernel, dim3(B_DIM / 4), dim3(256), 0, stream,
                       part, b, leafbf, S);
    hipLaunchKernelGGL(gemm2_kernel, dim3((KPAD / 128) * (B_DIM / 128)), dim3(256), 0, stream,
                       leafbf, dT, out);
}

// Round 6
// 276.280 us; speedup vs baseline: 1.8937x; 1.1049x over previous
//
#include <hip/hip_runtime.h>

// SoftDecisionTree (R6): fp32-direct GEMM1 staging, fp16 split-K partials,
// XOR-swizzled LDS, XCD-swizzled grids.
//   prep : Wb=bf16(W) padded, dT=softmax(leaf_params)^T
//   part = xs @ Wb^T (split-K=4, fp16 partials)    gemm1_kernel
//   lf   = tree(sigmoid(sum_s part + b))           reduce_tree_kernel (bf16 out)
//   out  = lf @ dT^T                               gemm2_kernel

typedef __bf16 bf16x8 __attribute__((ext_vector_type(8)));
typedef float f32x4 __attribute__((ext_vector_type(4)));
typedef _Float16 f16x8 __attribute__((ext_vector_type(8)));

#define B_DIM 8192
#define F_DIM 4096
#define NI 511
#define NL 512
#define K_DIM 1000
#define KPAD 1024
#define SPLIT 4
#define KCHUNK 1024

#define W_BLKS  1024    // 512*4096 / (256*8)
#define SM_BLKS 512

// RNE fp32->bf16 (prep / tree outputs)
__device__ inline unsigned short f2bf(float f) {
    unsigned int u = __float_as_uint(f);
    return (unsigned short)((u + 0x7FFFu + ((u >> 16) & 1u)) >> 16);
}
__device__ inline unsigned int pk_bf16(float a, float b) {
    return (unsigned int)f2bf(a) | ((unsigned int)f2bf(b) << 16);
}
// cheap round-half-up fp32 pair -> packed bf16x2 (2 adds + 1 perm)
__device__ inline unsigned int pk2_hu(float a, float b) {
    unsigned int ua = __float_as_uint(a) + 0x8000u;
    unsigned int ub = __float_as_uint(b) + 0x8000u;
    return __builtin_amdgcn_perm(ub, ua, 0x07060302u);
}

// async global->LDS, 16 B/lane; LDS dest = wave-uniform base + lane*16
typedef __attribute__((address_space(1))) const unsigned int guint;
typedef __attribute__((address_space(3))) unsigned int luint;
__device__ inline void gload16(const unsigned short* g, unsigned short* l) {
    __builtin_amdgcn_global_load_lds((guint*)g, (luint*)l, 16, 0, 0);
}
__device__ inline void gload16f(const float* g, float* l) {
    __builtin_amdgcn_global_load_lds((guint*)g, (luint*)l, 16, 0, 0);
}

// swizzled bf16 fragment load: granule(16B) index ^= row&7  -> conflict-free
__device__ inline bf16x8 ldb(const unsigned short* Lbase, int r, int kb) {
    const int g = (kb >> 3) ^ (r & 7);
    return *(const bf16x8*)&Lbase[r * 64 + g * 8];
}
// swizzled fp32 fragment load + cvt to bf16x8 (two 16B granules, ^= row&7)
__device__ inline bf16x8 lda32(const float* Lbase, int r, int kb) {
    const int rs = r & 7;
    const float* rowp = &Lbase[r * 64];
    const f32x4 lo = *(const f32x4*)&rowp[(((kb >> 2)    ) ^ rs) * 4];
    const f32x4 hi = *(const f32x4*)&rowp[(((kb >> 2) + 1) ^ rs) * 4];
    uint4 q;
    q.x = pk2_hu(lo.x, lo.y);
    q.y = pk2_hu(lo.z, lo.w);
    q.z = pk2_hu(hi.x, hi.y);
    q.w = pk2_hu(hi.z, hi.w);
    bf16x8 a;
    __builtin_memcpy(&a, &q, 16);
    return a;
}

__device__ inline float waveMax(float v) {
#pragma unroll
    for (int off = 32; off; off >>= 1) v = fmaxf(v, __shfl_down(v, off, 64));
    return v;
}
__device__ inline float waveSum(float v) {
#pragma unroll
    for (int off = 32; off; off >>= 1) v += __shfl_down(v, off, 64);
    return v;
}

// ---------------- prep: W->bf16 (512-row pad), softmax^T ----------------
__global__ __launch_bounds__(256) void prep_kernel(
    const float* __restrict__ W, unsigned short* __restrict__ Wb,
    const float* __restrict__ lp, unsigned short* __restrict__ dT)
{
    __shared__ float sred[8];
    const int bid = blockIdx.x;
    const int tid = threadIdx.x;

    if (bid < W_BLKS) {
        const size_t i = ((size_t)bid * 256 + tid) * 8;
        const int row = (int)(i >> 12);  // /4096
        uint4 h = {0u, 0u, 0u, 0u};
        if (row < NI) {
            const float4 a = *(const float4*)(W + i);
            const float4 b = *(const float4*)(W + i + 4);
            h.x = pk_bf16(a.x, a.y);
            h.y = pk_bf16(a.z, a.w);
            h.z = pk_bf16(b.x, b.y);
            h.w = pk_bf16(b.z, b.w);
        }
        *(uint4*)(Wb + i) = h;
        return;
    }
    // softmax + transpose: dT[n][k] = softmax(leaf_params[k])[n]
    const int k = bid - W_BLKS;
    const int lane = tid & 63;
    const int wave = tid >> 6;
    const float* rowp = lp + (size_t)k * K_DIM;

    float vals[4];
    float mx = -3.0e38f;
#pragma unroll
    for (int c = 0; c < 4; ++c) {
        const int n = tid + c * 256;
        vals[c] = (n < K_DIM) ? rowp[n] : -3.0e38f;
        mx = fmaxf(mx, vals[c]);
    }
    mx = waveMax(mx);
    if (lane == 0) sred[wave] = mx;
    __syncthreads();
    const float gmax = fmaxf(fmaxf(sred[0], sred[1]), fmaxf(sred[2], sred[3]));

    float sum = 0.f;
#pragma unroll
    for (int c = 0; c < 4; ++c) {
        const int n = tid + c * 256;
        const float e = (n < K_DIM) ? __expf(vals[c] - gmax) : 0.f;
        vals[c] = e;
        sum += e;
    }
    sum = waveSum(sum);
    if (lane == 0) sred[4 + wave] = sum;
    __syncthreads();
    const float inv = 1.0f / (sred[4] + sred[5] + sred[6] + sred[7]);
#pragma unroll
    for (int c = 0; c < 4; ++c) {
        const int n = tid + c * 256;
        if (n < K_DIM) dT[(size_t)n * NL + k] = f2bf(vals[c] * inv);
    }
}

// ---------------- GEMM1: part[z] = xs @ Wb^T, fp32-A direct staging ----------------
// grid 1024 = 8 xcd x 8 mhi x 4 z x 4 nt; m-rows partitioned per XCD.
__global__ __launch_bounds__(256) void gemm1_kernel(
    const float* __restrict__ A, const unsigned short* __restrict__ Bb,
    _Float16* __restrict__ part)
{
    __shared__ __align__(16) float Al[128 * 64];            // 32 KB
    __shared__ __align__(16) unsigned short Bl[128 * 64];   // 16 KB

    const int id = blockIdx.x;
    const int xcd = id & 7;
    const int jj = (id >> 3) & 15;
    const int mhi = id >> 7;
    const int z = jj >> 2;
    const int nt = jj & 3;
    const int m0 = (mhi * 8 + xcd) * 128;
    const int n0 = nt * 128;
    const int kbeg = z * KCHUNK;

    const int tid = threadIdx.x;
    const int lane = tid & 63;
    const int wave = tid >> 6;
    const int wm = (wave >> 1) * 64;
    const int wn = (wave & 1) * 64;
    const int quad = lane >> 4;
    const int l16 = lane & 15;

    // A staging (fp32): pass p covers rows p*16 + wave*4 + (lane>>4); source col
    // granule-of-4 = (lane&15) ^ ((wave*4+dr)&7)  [matches lda32 swizzle]
    const int dra = lane >> 4;
    const int ca = (((lane & 15) ^ ((wave * 4 + dra) & 7))) * 4;
    const float* gA = A + (size_t)(m0 + wave * 4 + dra) * F_DIM + kbeg + ca;
    float* lA = &Al[wave * 4 * 64];
    // B staging (bf16): pass p covers rows p*32 + wave*8 + (lane>>3); granule-of-8
    // = (lane&7) ^ dr  [matches ldb swizzle]
    const int drb = lane >> 3;
    const int cb = ((lane & 7) ^ drb) * 8;
    const unsigned short* gB = Bb + (size_t)(n0 + wave * 8 + drb) * F_DIM + kbeg + cb;
    unsigned short* lB = &Bl[wave * 8 * 64];

    const f32x4 zero = {0.f, 0.f, 0.f, 0.f};
    f32x4 acc[4][4];
#pragma unroll
    for (int i = 0; i < 4; ++i)
#pragma unroll
        for (int j2 = 0; j2 < 4; ++j2) acc[i][j2] = zero;

    for (int k0 = 0; k0 < KCHUNK; k0 += 64) {
#pragma unroll
        for (int p = 0; p < 8; ++p)
            gload16f(gA + k0 + (size_t)p * 16 * F_DIM, lA + p * 1024);
#pragma unroll
        for (int p = 0; p < 4; ++p)
            gload16(gB + k0 + (size_t)p * 32 * F_DIM, lB + p * 2048);
        __syncthreads();
#pragma unroll
        for (int kk = 0; kk < 64; kk += 32) {
            const int kb = kk + quad * 8;
            bf16x8 av[4], bv[4];
#pragma unroll
            for (int i = 0; i < 4; ++i)
                av[i] = lda32(Al, wm + i * 16 + l16, kb);
#pragma unroll
            for (int j2 = 0; j2 < 4; ++j2)
                bv[j2] = ldb(Bl, wn + j2 * 16 + l16, kb);
#pragma unroll
            for (int i = 0; i < 4; ++i)
#pragma unroll
                for (int j2 = 0; j2 < 4; ++j2)
                    acc[i][j2] = __builtin_amdgcn_mfma_f32_16x16x32_bf16(av[i], bv[j2], acc[i][j2], 0, 0, 0);
        }
        __syncthreads();
    }

    _Float16* dst = part + (size_t)z * ((size_t)B_DIM * NL);
#pragma unroll
    for (int i = 0; i < 4; ++i) {
        const int mbase = m0 + wm + i * 16 + quad * 4;
#pragma unroll
        for (int j2 = 0; j2 < 4; ++j2) {
            const int n = n0 + wn + j2 * 16 + l16;
#pragma unroll
            for (int r = 0; r < 4; ++r)
                dst[(size_t)(mbase + r) * NL + n] = (_Float16)acc[i][j2][r];
        }
    }
}

// ---------------- fused reduce(fp16 partials) + bias + sigmoid + tree ----------------
__global__ __launch_bounds__(256) void reduce_tree_kernel(
    const _Float16* __restrict__ part, const float* __restrict__ bvec,
    unsigned short* __restrict__ leafbf)
{
    __shared__ float bsh[NL];
    __shared__ float prow[4][NL];

    const int tid = threadIdx.x;
    bsh[tid] = (tid < NI) ? bvec[tid] : 0.0f;
    const int t2 = tid + 256;
    bsh[t2] = (t2 < NI) ? bvec[t2] : 0.0f;

    const int wave = tid >> 6;
    const int lane = tid & 63;
    const int row = blockIdx.x * 4 + wave;
    const size_t base = (size_t)row * NL + lane * 8;

    float v[8] = {0.f, 0.f, 0.f, 0.f, 0.f, 0.f, 0.f, 0.f};
#pragma unroll
    for (int s = 0; s < SPLIT; ++s) {
        const f16x8 h = *(const f16x8*)(part + (size_t)s * ((size_t)B_DIM * NL) + base);
#pragma unroll
        for (int e = 0; e < 8; ++e) v[e] += (float)h[e];
    }
    __syncthreads();

#pragma unroll
    for (int i = 0; i < 8; ++i) {
        const float x = v[i] + bsh[lane * 8 + i];
        prow[wave][lane * 8 + i] = 1.0f / (1.0f + __expf(-x));
    }
    __syncthreads();

    const float* pr = prow[wave];
    float pre = 1.0f;
    int pnode = 0;
#pragma unroll
    for (int t = 5; t >= 0; --t) {
        const int bit = (lane >> t) & 1;
        const float p = pr[pnode];
        pre *= bit ? p : (1.0f - p);
        pnode = 2 * pnode + 1 + bit;
    }
    unsigned short outs[8];
#pragma unroll
    for (int jj = 0; jj < 8; ++jj) {
        float prob = pre;
        int node = pnode;
#pragma unroll
        for (int t = 2; t >= 0; --t) {
            const int bit = (jj >> t) & 1;
            const float p = pr[node];
            prob *= bit ? p : (1.0f - p);
            node = 2 * node + 1 + bit;
        }
        outs[jj] = f2bf(prob);
    }
    uint4 r;
    r.x = (unsigned int)outs[0] | ((unsigned int)outs[1] << 16);
    r.y = (unsigned int)outs[2] | ((unsigned int)outs[3] << 16);
    r.z = (unsigned int)outs[4] | ((unsigned int)outs[5] << 16);
    r.w = (unsigned int)outs[6] | ((unsigned int)outs[7] << 16);
    *(uint4*)(leafbf + (size_t)row * NL + lane * 8) = r;
}

// ---------------- GEMM2: out = leaf_prob @ dists ----------------
// grid 512 = 8 xcd x 8 mhi x 8 nt; swizzled LDS; masked fp32 stores at n>=1000.
__global__ __launch_bounds__(256) void gemm2_kernel(
    const unsigned short* __restrict__ A, const unsigned short* __restrict__ Bm,
    float* __restrict__ out)
{
    __shared__ __align__(16) unsigned short Al[128 * 64];
    __shared__ __align__(16) unsigned short Bl[128 * 64];

    const int id = blockIdx.x;
    const int xcd = id & 7;
    const int j = id >> 3;
    const int nt = j & 7;
    const int mhi = j >> 3;
    const int m0 = (mhi * 8 + xcd) * 128;
    const int n0 = nt * 128;

    const int tid = threadIdx.x;
    const int lane = tid & 63;
    const int wave = tid >> 6;
    const int wm = (wave >> 1) * 64;
    const int wn = (wave & 1) * 64;
    const int quad = lane >> 4;
    const int l16 = lane & 15;

    const int drb = lane >> 3;
    const int cb = ((lane & 7) ^ drb) * 8;
    const unsigned short* gA = A + (size_t)(m0 + wave * 8 + drb) * NL + cb;
    const unsigned short* gB = Bm + (size_t)(n0 + wave * 8 + drb) * NL + cb;
    unsigned short* lA = &Al[wave * 8 * 64];
    unsigned short* lB = &Bl[wave * 8 * 64];

    const f32x4 zero = {0.f, 0.f, 0.f, 0.f};
    f32x4 acc[4][4];
#pragma unroll
    for (int i = 0; i < 4; ++i)
#pragma unroll
        for (int j2 = 0; j2 < 4; ++j2) acc[i][j2] = zero;

    for (int k0 = 0; k0 < NL; k0 += 64) {
#pragma unroll
        for (int p = 0; p < 4; ++p) {
            gload16(gA + k0 + (size_t)p * 32 * NL, lA + p * 2048);
            gload16(gB + k0 + (size_t)p * 32 * NL, lB + p * 2048);
        }
        __syncthreads();
#pragma unroll
        for (int kk = 0; kk < 64; kk += 32) {
            const int kb = kk + quad * 8;
            bf16x8 av[4], bv[4];
#pragma unroll
            for (int i = 0; i < 4; ++i)
                av[i] = ldb(Al, wm + i * 16 + l16, kb);
#pragma unroll
            for (int j2 = 0; j2 < 4; ++j2)
                bv[j2] = ldb(Bl, wn + j2 * 16 + l16, kb);
#pragma unroll
            for (int i = 0; i < 4; ++i)
#pragma unroll
                for (int j2 = 0; j2 < 4; ++j2)
                    acc[i][j2] = __builtin_amdgcn_mfma_f32_16x16x32_bf16(av[i], bv[j2], acc[i][j2], 0, 0, 0);
        }
        __syncthreads();
    }

#pragma unroll
    for (int i = 0; i < 4; ++i) {
        const int mbase = m0 + wm + i * 16 + quad * 4;
#pragma unroll
        for (int j2 = 0; j2 < 4; ++j2) {
            const int n = n0 + wn + j2 * 16 + l16;
            if (n < K_DIM) {
#pragma unroll
                for (int r = 0; r < 4; ++r)
                    out[(size_t)(mbase + r) * K_DIM + n] = acc[i][j2][r];
            }
        }
    }
}

extern "C" void kernel_launch(void* const* d_in, const int* in_sizes, int n_in,
                              void* d_out, int out_size, void* d_ws, size_t ws_size,
                              hipStream_t stream) {
    const float* xs = (const float*)d_in[0];
    const float* W  = (const float*)d_in[1];
    const float* b  = (const float*)d_in[2];
    const float* lp = (const float*)d_in[3];
    float* out = (float*)d_out;

    const size_t partB = (size_t)B_DIM * NL * 2;   //  8 MiB per slice (fp16)
    const size_t leafB = (size_t)B_DIM * NL * 2;   //  8 MiB
    const size_t dTB   = (size_t)KPAD * NL * 2;    //  1 MiB

    char* ws = (char*)d_ws;
    _Float16* part = (_Float16*)ws;
    unsigned short* leafbf = (unsigned short*)(ws + SPLIT * partB);
    unsigned short* dT = (unsigned short*)(ws + SPLIT * partB + leafB);
    unsigned short* Wb = (unsigned short*)(ws + SPLIT * partB + leafB + dTB);
    (void)ws_size;  // needs ~45 MiB; harness provides 512 MiB

    hipLaunchKernelGGL(prep_kernel, dim3(W_BLKS + SM_BLKS), dim3(256), 0, stream,
                       W, Wb, lp, dT);
    hipLaunchKernelGGL(gemm1_kernel, dim3(8 * 8 * 4 * 4), dim3(256), 0, stream,
                       xs, Wb, part);
    hipLaunchKernelGGL(reduce_tree_kernel, dim3(B_DIM / 4), dim3(256), 0, stream,
                       part, b, leafbf);
    hipLaunchKernelGGL(gemm2_kernel, dim3(8 * 8 * 8), dim3(256), 0, stream,
                       leafbf, dT, out);
}